// Round 7
// baseline (2653.410 us; speedup 1.0000x reference)
//
#include <hip/hip_runtime.h>
#include <hip/hip_bf16.h>

#define D 128
#define BROWS 64              // rows per bucket
#define MAXNB 1600            // >= ceil(100000/64)=1563
#define GRID_SC 250           // scatter blocks (contiguous edge segments)

typedef __attribute__((ext_vector_type(8))) short short8v;
typedef __attribute__((ext_vector_type(4))) float floatx4;

__device__ inline short f2bf(float f) {
    union { float f; unsigned u; } v; v.f = f;
    unsigned r = v.u + 0x7fffu + ((v.u >> 16) & 1u);   // RNE
    return (short)(r >> 16);
}
__device__ inline float bf2f(short h) {
    union { unsigned u; float f; } v;
    v.u = ((unsigned)(unsigned short)h) << 16;
    return v.f;
}

// ---------------------------------------------------------------------------
// W convert: Whb[0..127][k]=W, Whb[128..255][k]=Ws  (bf16 bits as short)
// ---------------------------------------------------------------------------
__global__ __launch_bounds__(256) void convert_w(
    const float* __restrict__ W, const float* __restrict__ Ws,
    short* __restrict__ Whb)
{
    const int i = blockIdx.x * 256 + threadIdx.x;
    if (i < D * D) {
        Whb[i] = f2bf(W[i]);
        Whb[D * D + i] = f2bf(Ws[i]);
    }
}

// ---------------------------------------------------------------------------
// MFMA GEMM: 64 rows x 256 cols per block.
// cols 0-127 -> yh (bf16), cols 128-255 -> x2 (f32, into d_out)
// ---------------------------------------------------------------------------
__global__ __launch_bounds__(256) void gemm_mfma(
    const float* __restrict__ x, const short* __restrict__ Whb,
    const float* __restrict__ bW, const float* __restrict__ bs,
    short* __restrict__ yh, float* __restrict__ out, int N)
{
    const int l  = threadIdx.x & 63;
    const int w  = threadIdx.x >> 6;
    const int r0 = blockIdx.x * 64 + w * 16;
    const int lr = l & 15;
    const int lk = l >> 4;

    const int arow = r0 + lr;
    const int arow_c = arow < N ? arow : N - 1;
    const float* xr = x + (size_t)arow_c * D;

    short8v afrag[4];
#pragma unroll
    for (int kc = 0; kc < 4; ++kc) {
        const float4 f0 = *(const float4*)(xr + kc * 32 + lk * 8);
        const float4 f1 = *(const float4*)(xr + kc * 32 + lk * 8 + 4);
        short8v a;
        a[0] = f2bf(f0.x); a[1] = f2bf(f0.y); a[2] = f2bf(f0.z); a[3] = f2bf(f0.w);
        a[4] = f2bf(f1.x); a[5] = f2bf(f1.y); a[6] = f2bf(f1.z); a[7] = f2bf(f1.w);
        afrag[kc] = a;
    }

#pragma unroll
    for (int ct = 0; ct < 16; ++ct) {
        const short* wrow = Whb + (size_t)(ct * 16 + lr) * D;
        floatx4 acc = {0.f, 0.f, 0.f, 0.f};
#pragma unroll
        for (int kc = 0; kc < 4; ++kc) {
            const short8v b = *(const short8v*)(wrow + kc * 32 + lk * 8);
            acc = __builtin_amdgcn_mfma_f32_16x16x32_bf16(afrag[kc], b, acc, 0, 0, 0);
        }
        const int col  = (ct & 7) * 16 + lr;
        const float bias = (ct < 8) ? bW[col] : bs[col];
#pragma unroll
        for (int r = 0; r < 4; ++r) {
            const int row = r0 + lk * 4 + r;
            if (row < N) {
                if (ct < 8) yh[(size_t)row * D + col] = f2bf(acc[r] + bias);
                else        out[(size_t)row * D + col] = acc[r] + bias;
            }
        }
    }
}

// ---------------------------------------------------------------------------
// Bucket histogram, LDS-privatized. bucket = row >> 6.
// ---------------------------------------------------------------------------
__global__ __launch_bounds__(256) void hist_kernel(
    const int* __restrict__ row, unsigned* __restrict__ cnt, int E, int nb)
{
    __shared__ unsigned h[MAXNB];
    for (int i = threadIdx.x; i < nb; i += 256) h[i] = 0u;
    __syncthreads();
    for (int e = blockIdx.x * 256 + threadIdx.x; e < E; e += gridDim.x * 256)
        atomicAdd(&h[(unsigned)row[e] >> 6], 1u);
    __syncthreads();
    for (int i = threadIdx.x; i < nb; i += 256) {
        const unsigned v = h[i];
        if (v) atomicAdd(&cnt[i], v);
    }
}

// ---------------------------------------------------------------------------
// Single-block scan over nb buckets -> bucketStart[nb+1], gCursor[nb]
// ---------------------------------------------------------------------------
__global__ __launch_bounds__(256) void scan_kernel(
    const unsigned* __restrict__ cnt, unsigned* __restrict__ bucketStart,
    unsigned* __restrict__ gCursor, int nb)
{
    __shared__ unsigned s[256];
    const int t = threadIdx.x;
    unsigned loc[7];
    unsigned sum = 0;
#pragma unroll
    for (int i = 0; i < 7; ++i) {
        const int idx = t * 7 + i;
        loc[i] = (idx < nb) ? cnt[idx] : 0u;
        sum += loc[i];
    }
    s[t] = sum; __syncthreads();
    for (int off = 1; off < 256; off <<= 1) {
        const unsigned u = (t >= off) ? s[t - off] : 0u;
        __syncthreads();
        s[t] += u;
        __syncthreads();
    }
    unsigned base = s[t] - sum;
#pragma unroll
    for (int i = 0; i < 7; ++i) {
        const int idx = t * 7 + i;
        if (idx < nb) { bucketStart[idx] = base; gCursor[idx] = base; }
        base += loc[i];
    }
    if (t == 255) bucketStart[nb] = base;
}

// ---------------------------------------------------------------------------
// Two-pass block-privatized scatter. Each block owns a contiguous edge
// segment; pass1 counts per-bucket in LDS, reserves chunks via ONE global
// atomic per bucket, pass2 places edges via LDS cursors.
// pack word0 = col | (row&63)<<17 ; word1 = val bits.
// ---------------------------------------------------------------------------
__global__ __launch_bounds__(256) void scatter_kernel(
    const int* __restrict__ row, const int* __restrict__ col,
    const float* __restrict__ val, unsigned* __restrict__ gCursor,
    int2* __restrict__ pack, int E, int nb)
{
    __shared__ unsigned cntL[MAXNB];
    __shared__ unsigned curL[MAXNB];
    const int seg = (E + gridDim.x - 1) / gridDim.x;
    const int s0  = blockIdx.x * seg;
    const int s1  = min(E, s0 + seg);

    for (int i = threadIdx.x; i < nb; i += 256) cntL[i] = 0u;
    __syncthreads();
    for (int e = s0 + threadIdx.x; e < s1; e += 256)
        atomicAdd(&cntL[(unsigned)row[e] >> 6], 1u);
    __syncthreads();
    for (int i = threadIdx.x; i < nb; i += 256) {
        const unsigned c = cntL[i];
        curL[i] = c ? atomicAdd(&gCursor[i], c) : 0u;
    }
    __syncthreads();
    for (int e = s0 + threadIdx.x; e < s1; e += 256) {
        const unsigned r = (unsigned)row[e];
        const unsigned pos = atomicAdd(&curL[r >> 6], 1u);
        pack[pos] = make_int2(col[e] | (int)((r & 63u) << 17), __float_as_int(val[e]));
    }
}

// ---------------------------------------------------------------------------
// Bucket-local aggregate: one block per bucket, 64x128 f32 acc in LDS.
// One edge per wave-iteration: 64 lanes x ushort2 (256B contiguous y-row),
// ds atomic accumulate; fused x2 + relu epilogue.
// ---------------------------------------------------------------------------
__global__ __launch_bounds__(256) void aggregate_kernel(
    const short* __restrict__ yh, const int2* __restrict__ pack,
    const unsigned* __restrict__ bucketStart,
    float* __restrict__ out, int N)
{
    __shared__ float acc[BROWS * D];
    const int b = blockIdx.x;
    const int t = threadIdx.x;
    const int w = t >> 6;
    const int l = t & 63;

    {
        float4* a4 = (float4*)acc;
#pragma unroll
        for (int i = 0; i < 8; ++i) a4[t + 256 * i] = make_float4(0.f, 0.f, 0.f, 0.f);
    }
    __syncthreads();

    const unsigned eStart = bucketStart[b];
    const unsigned eEnd   = bucketStart[b + 1];

    for (unsigned e = eStart + (unsigned)w; e < eEnd; e += 4) {
        const int2 p = pack[e];                       // wave-uniform
        const int  col = p.x & 0x1FFFF;
        const int  rlo = (unsigned)p.x >> 17;
        const float v  = __int_as_float(p.y);
        const ushort2 yv = *(const ushort2*)(yh + (size_t)col * D + l * 2);
        const float y0 = bf2f((short)yv.x);
        const float y1 = bf2f((short)yv.y);
        atomicAdd(&acc[rlo * D + l * 2],     v * y0);
        atomicAdd(&acc[rlo * D + l * 2 + 1], v * y1);
    }
    __syncthreads();

    // epilogue: out = relu(acc + x2), x2 already in d_out
    const int rBase = b * BROWS;
#pragma unroll
    for (int i = 0; i < 8; ++i) {
        const int idx4 = t + 256 * i;           // float4 index into 64x128
        const int rlo  = idx4 >> 5;             // 32 float4 per row
        const int c4   = idx4 & 31;
        const int r    = rBase + rlo;
        if (r < N) {
            float* op = out + (size_t)r * D + c4 * 4;
            const float4 a = ((const float4*)acc)[idx4];
            const float4 x2 = *(const float4*)op;
            float4 o;
            o.x = a.x + x2.x; o.y = a.y + x2.y;
            o.z = a.z + x2.z; o.w = a.w + x2.w;
            o.x = o.x > 0.f ? o.x : 0.f;  o.y = o.y > 0.f ? o.y : 0.f;
            o.z = o.z > 0.f ? o.z : 0.f;  o.w = o.w > 0.f ? o.w : 0.f;
            *(float4*)op = o;
        }
    }
}

// ---------------------------------------------------------------------------
extern "C" void kernel_launch(void* const* d_in, const int* in_sizes, int n_in,
                              void* d_out, int out_size, void* d_ws, size_t ws_size,
                              hipStream_t stream)
{
    const float* x        = (const float*)d_in[0];
    const int*   edge_row = (const int*)  d_in[1];
    const int*   edge_col = (const int*)  d_in[2];
    const float* edge_val = (const float*)d_in[3];
    const float* W        = (const float*)d_in[4];
    const float* bW       = (const float*)d_in[5];
    const float* Ws       = (const float*)d_in[6];
    const float* bs       = (const float*)d_in[7];
    float* out = (float*)d_out;

    const int N  = in_sizes[0] / D;                 // 100000
    const int E  = in_sizes[1];                     // 3200000
    const int NB = (N + BROWS - 1) / BROWS;         // 1563

    // workspace layout
    short*    yh          = (short*)d_ws;                     // N*D bf16
    short*    Whb         = yh + (size_t)N * D;               // 2*D*D bf16
    unsigned* cnt         = (unsigned*)(Whb + 2 * D * D);     // NB
    unsigned* bucketStart = cnt + MAXNB;                      // NB+1
    unsigned* gCursor     = bucketStart + MAXNB + 1;          // NB
    int2*     pack        = (int2*)(gCursor + MAXNB);         // E

    hipLaunchKernelGGL(convert_w, dim3((D * D + 255) / 256), dim3(256), 0, stream,
                       W, Ws, Whb);
    hipLaunchKernelGGL(gemm_mfma, dim3((N + 63) / 64), dim3(256), 0, stream,
                       x, Whb, bW, bs, yh, out, N);

    hipMemsetAsync(cnt, 0, (size_t)NB * sizeof(unsigned), stream);
    hipLaunchKernelGGL(hist_kernel, dim3(256), dim3(256), 0, stream,
                       edge_row, cnt, E, NB);
    hipLaunchKernelGGL(scan_kernel, dim3(1), dim3(256), 0, stream,
                       cnt, bucketStart, gCursor, NB);
    hipLaunchKernelGGL(scatter_kernel, dim3(GRID_SC), dim3(256), 0, stream,
                       edge_row, edge_col, edge_val, gCursor, pack, E, NB);

    hipLaunchKernelGGL(aggregate_kernel, dim3(NB), dim3(256), 0, stream,
                       yh, pack, bucketStart, out, N);
}

// Round 8
// 2506.329 us; speedup vs baseline: 1.0587x; 1.0587x over previous
//
#include <hip/hip_runtime.h>
#include <hip/hip_bf16.h>

#define D 128
#define BROWS 32              // rows per bucket (16 KB LDS accumulator)
#define MAXNB 3200            // >= ceil(100000/32)=3125
#define GRID_SC 250           // scatter blocks (contiguous edge segments)
#define AGG_BATCH 8           // edges in flight per wave iteration

typedef __attribute__((ext_vector_type(8))) short short8v;
typedef __attribute__((ext_vector_type(4))) float floatx4;

__device__ inline short f2bf(float f) {
    union { float f; unsigned u; } v; v.f = f;
    unsigned r = v.u + 0x7fffu + ((v.u >> 16) & 1u);   // RNE
    return (short)(r >> 16);
}
__device__ inline float bf2f(short h) {
    union { unsigned u; float f; } v;
    v.u = ((unsigned)(unsigned short)h) << 16;
    return v.f;
}

// ---------------------------------------------------------------------------
// W convert: Whb[0..127][k]=W, Whb[128..255][k]=Ws  (bf16 bits as short)
// ---------------------------------------------------------------------------
__global__ __launch_bounds__(256) void convert_w(
    const float* __restrict__ W, const float* __restrict__ Ws,
    short* __restrict__ Whb)
{
    const int i = blockIdx.x * 256 + threadIdx.x;
    if (i < D * D) {
        Whb[i] = f2bf(W[i]);
        Whb[D * D + i] = f2bf(Ws[i]);
    }
}

// ---------------------------------------------------------------------------
// MFMA GEMM: 64 rows x 256 cols per block.
// cols 0-127 -> yh (bf16), cols 128-255 -> x2 (f32, into d_out)
// ---------------------------------------------------------------------------
__global__ __launch_bounds__(256) void gemm_mfma(
    const float* __restrict__ x, const short* __restrict__ Whb,
    const float* __restrict__ bW, const float* __restrict__ bs,
    short* __restrict__ yh, float* __restrict__ out, int N)
{
    const int l  = threadIdx.x & 63;
    const int w  = threadIdx.x >> 6;
    const int r0 = blockIdx.x * 64 + w * 16;
    const int lr = l & 15;
    const int lk = l >> 4;

    const int arow = r0 + lr;
    const int arow_c = arow < N ? arow : N - 1;
    const float* xr = x + (size_t)arow_c * D;

    short8v afrag[4];
#pragma unroll
    for (int kc = 0; kc < 4; ++kc) {
        const float4 f0 = *(const float4*)(xr + kc * 32 + lk * 8);
        const float4 f1 = *(const float4*)(xr + kc * 32 + lk * 8 + 4);
        short8v a;
        a[0] = f2bf(f0.x); a[1] = f2bf(f0.y); a[2] = f2bf(f0.z); a[3] = f2bf(f0.w);
        a[4] = f2bf(f1.x); a[5] = f2bf(f1.y); a[6] = f2bf(f1.z); a[7] = f2bf(f1.w);
        afrag[kc] = a;
    }

#pragma unroll
    for (int ct = 0; ct < 16; ++ct) {
        const short* wrow = Whb + (size_t)(ct * 16 + lr) * D;
        floatx4 acc = {0.f, 0.f, 0.f, 0.f};
#pragma unroll
        for (int kc = 0; kc < 4; ++kc) {
            const short8v b = *(const short8v*)(wrow + kc * 32 + lk * 8);
            acc = __builtin_amdgcn_mfma_f32_16x16x32_bf16(afrag[kc], b, acc, 0, 0, 0);
        }
        const int col  = (ct & 7) * 16 + lr;
        const float bias = (ct < 8) ? bW[col] : bs[col];
#pragma unroll
        for (int r = 0; r < 4; ++r) {
            const int row = r0 + lk * 4 + r;
            if (row < N) {
                if (ct < 8) yh[(size_t)row * D + col] = f2bf(acc[r] + bias);
                else        out[(size_t)row * D + col] = acc[r] + bias;
            }
        }
    }
}

// ---------------------------------------------------------------------------
// Bucket histogram, LDS-privatized. bucket = row >> 5.
// ---------------------------------------------------------------------------
__global__ __launch_bounds__(256) void hist_kernel(
    const int* __restrict__ row, unsigned* __restrict__ cnt, int E, int nb)
{
    __shared__ unsigned h[MAXNB];
    for (int i = threadIdx.x; i < nb; i += 256) h[i] = 0u;
    __syncthreads();
    for (int e = blockIdx.x * 256 + threadIdx.x; e < E; e += gridDim.x * 256)
        atomicAdd(&h[(unsigned)row[e] >> 5], 1u);
    __syncthreads();
    for (int i = threadIdx.x; i < nb; i += 256) {
        const unsigned v = h[i];
        if (v) atomicAdd(&cnt[i], v);
    }
}

// ---------------------------------------------------------------------------
// Single-block scan over nb buckets -> bucketStart[nb+1], gCursor[nb]
// ---------------------------------------------------------------------------
__global__ __launch_bounds__(256) void scan_kernel(
    const unsigned* __restrict__ cnt, unsigned* __restrict__ bucketStart,
    unsigned* __restrict__ gCursor, int nb)
{
    __shared__ unsigned s[256];
    const int t = threadIdx.x;
    unsigned loc[13];
    unsigned sum = 0;
#pragma unroll
    for (int i = 0; i < 13; ++i) {
        const int idx = t * 13 + i;
        loc[i] = (idx < nb) ? cnt[idx] : 0u;
        sum += loc[i];
    }
    s[t] = sum; __syncthreads();
    for (int off = 1; off < 256; off <<= 1) {
        const unsigned u = (t >= off) ? s[t - off] : 0u;
        __syncthreads();
        s[t] += u;
        __syncthreads();
    }
    unsigned base = s[t] - sum;
#pragma unroll
    for (int i = 0; i < 13; ++i) {
        const int idx = t * 13 + i;
        if (idx < nb) { bucketStart[idx] = base; gCursor[idx] = base; }
        base += loc[i];
    }
    if (t == 255) bucketStart[nb] = base;
}

// ---------------------------------------------------------------------------
// Two-pass block-privatized scatter. Each block owns a contiguous edge
// segment; pass1 counts per-bucket in LDS, reserves chunks with ONE global
// atomic per touched bucket, pass2 places edges via LDS cursors.
// pack word0 = col | (row&31)<<17 ; word1 = val bits.
// ---------------------------------------------------------------------------
__global__ __launch_bounds__(256) void scatter_kernel(
    const int* __restrict__ row, const int* __restrict__ col,
    const float* __restrict__ val, unsigned* __restrict__ gCursor,
    int2* __restrict__ pack, int E, int nb)
{
    __shared__ unsigned cntL[MAXNB];
    __shared__ unsigned curL[MAXNB];
    const int seg = (E + gridDim.x - 1) / gridDim.x;
    const int s0  = blockIdx.x * seg;
    const int s1  = min(E, s0 + seg);

    for (int i = threadIdx.x; i < nb; i += 256) cntL[i] = 0u;
    __syncthreads();
    for (int e = s0 + threadIdx.x; e < s1; e += 256)
        atomicAdd(&cntL[(unsigned)row[e] >> 5], 1u);
    __syncthreads();
    for (int i = threadIdx.x; i < nb; i += 256) {
        const unsigned c = cntL[i];
        curL[i] = c ? atomicAdd(&gCursor[i], c) : 0u;
    }
    __syncthreads();
    for (int e = s0 + threadIdx.x; e < s1; e += 256) {
        const unsigned r = (unsigned)row[e];
        const unsigned pos = atomicAdd(&curL[r >> 5], 1u);
        pack[pos] = make_int2(col[e] | (int)((r & 31u) << 17), __float_as_int(val[e]));
    }
}

// ---------------------------------------------------------------------------
// Bucket-local aggregate: one block per bucket, 32x128 f32 acc in LDS (16KB).
// Each wave processes AGG_BATCH edges per iteration: all pack loads issued,
// then all y-row gathers issued (independent, 8 in flight), then LDS atomics.
// Fused x2 + relu epilogue.
// ---------------------------------------------------------------------------
__global__ __launch_bounds__(256) void aggregate_kernel(
    const short* __restrict__ yh, const int2* __restrict__ pack,
    const unsigned* __restrict__ bucketStart,
    float* __restrict__ out, int N)
{
    __shared__ float acc[BROWS * D];
    const int b = blockIdx.x;
    const int t = threadIdx.x;
    const int w = t >> 6;
    const int l = t & 63;

    {
        float4* a4 = (float4*)acc;
#pragma unroll
        for (int i = 0; i < 4; ++i) a4[t + 256 * i] = make_float4(0.f, 0.f, 0.f, 0.f);
    }
    __syncthreads();

    const unsigned eStart = bucketStart[b];
    const unsigned eEnd   = bucketStart[b + 1];

    for (unsigned e0 = eStart + (unsigned)w * AGG_BATCH; e0 < eEnd;
         e0 += 4u * AGG_BATCH) {
        int2 p[AGG_BATCH];
#pragma unroll
        for (int j = 0; j < AGG_BATCH; ++j) {
            const unsigned idx = e0 + (unsigned)j;
            p[j] = (idx < eEnd) ? pack[idx] : make_int2(0, 0);  // val=0 -> no-op
        }
        ushort2 raw[AGG_BATCH];
#pragma unroll
        for (int j = 0; j < AGG_BATCH; ++j) {
            const int col = p[j].x & 0x1FFFF;
            raw[j] = *(const ushort2*)(yh + (size_t)col * D + l * 2);
        }
#pragma unroll
        for (int j = 0; j < AGG_BATCH; ++j) {
            const int   rlo = (unsigned)p[j].x >> 17;
            const float v   = __int_as_float(p[j].y);
            atomicAdd(&acc[rlo * D + l * 2],     v * bf2f((short)raw[j].x));
            atomicAdd(&acc[rlo * D + l * 2 + 1], v * bf2f((short)raw[j].y));
        }
    }
    __syncthreads();

    // epilogue: out = relu(acc + x2), x2 already in d_out
    const int rBase = b * BROWS;
#pragma unroll
    for (int i = 0; i < 4; ++i) {
        const int idx4 = t + 256 * i;           // float4 index into 32x128
        const int rlo  = idx4 >> 5;             // 32 float4 per row
        const int c4   = idx4 & 31;
        const int r    = rBase + rlo;
        if (r < N) {
            float* op = out + (size_t)r * D + c4 * 4;
            const float4 a = ((const float4*)acc)[idx4];
            const float4 x2 = *(const float4*)op;
            float4 o;
            o.x = a.x + x2.x; o.y = a.y + x2.y;
            o.z = a.z + x2.z; o.w = a.w + x2.w;
            o.x = o.x > 0.f ? o.x : 0.f;  o.y = o.y > 0.f ? o.y : 0.f;
            o.z = o.z > 0.f ? o.z : 0.f;  o.w = o.w > 0.f ? o.w : 0.f;
            *(float4*)op = o;
        }
    }
}

// ---------------------------------------------------------------------------
extern "C" void kernel_launch(void* const* d_in, const int* in_sizes, int n_in,
                              void* d_out, int out_size, void* d_ws, size_t ws_size,
                              hipStream_t stream)
{
    const float* x        = (const float*)d_in[0];
    const int*   edge_row = (const int*)  d_in[1];
    const int*   edge_col = (const int*)  d_in[2];
    const float* edge_val = (const float*)d_in[3];
    const float* W        = (const float*)d_in[4];
    const float* bW       = (const float*)d_in[5];
    const float* Ws       = (const float*)d_in[6];
    const float* bs       = (const float*)d_in[7];
    float* out = (float*)d_out;

    const int N  = in_sizes[0] / D;                 // 100000
    const int E  = in_sizes[1];                     // 3200000
    const int NB = (N + BROWS - 1) / BROWS;         // 3125

    // workspace layout
    short*    yh          = (short*)d_ws;                     // N*D bf16
    short*    Whb         = yh + (size_t)N * D;               // 2*D*D bf16
    unsigned* cnt         = (unsigned*)(Whb + 2 * D * D);     // NB
    unsigned* bucketStart = cnt + MAXNB;                      // NB+1
    unsigned* gCursor     = bucketStart + MAXNB + 1;          // NB
    int2*     pack        = (int2*)(gCursor + MAXNB);         // E

    hipLaunchKernelGGL(convert_w, dim3((D * D + 255) / 256), dim3(256), 0, stream,
                       W, Ws, Whb);
    hipLaunchKernelGGL(gemm_mfma, dim3((N + 63) / 64), dim3(256), 0, stream,
                       x, Whb, bW, bs, yh, out, N);

    hipMemsetAsync(cnt, 0, (size_t)NB * sizeof(unsigned), stream);
    hipLaunchKernelGGL(hist_kernel, dim3(256), dim3(256), 0, stream,
                       edge_row, cnt, E, NB);
    hipLaunchKernelGGL(scan_kernel, dim3(1), dim3(256), 0, stream,
                       cnt, bucketStart, gCursor, NB);
    hipLaunchKernelGGL(scatter_kernel, dim3(GRID_SC), dim3(256), 0, stream,
                       edge_row, edge_col, edge_val, gCursor, pack, E, NB);

    hipLaunchKernelGGL(aggregate_kernel, dim3(NB), dim3(256), 0, stream,
                       yh, pack, bucketStart, out, N);
}